// Round 1
// baseline (1286.677 us; speedup 1.0000x reference)
//
#include <hip/hip_runtime.h>
#include <hip/hip_bf16.h>
#include <math.h>

#define LN_EPS 1e-5f

// LayerNorm over D register values, then *g + b, then ReLU (in place).
template<int D>
__device__ __forceinline__ void ln_relu(float (&v)[D],
                                        const float* __restrict__ g,
                                        const float* __restrict__ b) {
    float m = 0.f;
#pragma unroll
    for (int i = 0; i < D; ++i) m += v[i];
    m *= (1.0f / (float)D);
    float var = 0.f;
#pragma unroll
    for (int i = 0; i < D; ++i) { float d = v[i] - m; var = fmaf(d, d, var); }
    var *= (1.0f / (float)D);
    const float rs = rsqrtf(var + LN_EPS);
#pragma unroll
    for (int i = 0; i < D; ++i) {
        float t = fmaf((v[i] - m) * rs, g[i], b[i]);
        v[i] = fmaxf(t, 0.f);
    }
}

// y[OUT] = x[IN] @ W[IN,OUT]   (row-major W, no bias)
template<int IN, int OUT>
__device__ __forceinline__ void matvec(const float (&x)[IN],
                                       const float* __restrict__ W,
                                       float (&y)[OUT]) {
#pragma unroll
    for (int j = 0; j < OUT; ++j) y[j] = 0.f;
#pragma unroll
    for (int k = 0; k < IN; ++k) {
        const float xv = x[k];
#pragma unroll
        for (int j = 0; j < OUT; ++j) y[j] = fmaf(xv, W[k * OUT + j], y[j]);
    }
}

// y[OUT] = x[IN] @ W[IN,OUT] + bias
template<int IN, int OUT>
__device__ __forceinline__ void matvec_bias(const float (&x)[IN],
                                            const float* __restrict__ W,
                                            const float* __restrict__ bias,
                                            float (&y)[OUT]) {
#pragma unroll
    for (int j = 0; j < OUT; ++j) y[j] = bias[j];
#pragma unroll
    for (int k = 0; k < IN; ++k) {
        const float xv = x[k];
#pragma unroll
        for (int j = 0; j < OUT; ++j) y[j] = fmaf(xv, W[k * OUT + j], y[j]);
    }
}

__global__ __launch_bounds__(256) void opening_critic_kernel(
    const float* __restrict__ rep,      // [N,128]
    const float* __restrict__ pose,     // [N,6]
    const float* __restrict__ opening,  // [N,1]
    const float* __restrict__ kw1, const float* __restrict__ kg,  const float* __restrict__ kb,
    const float* __restrict__ kw2, const float* __restrict__ kb2,
    const float* __restrict__ qw1, const float* __restrict__ qg,  const float* __restrict__ qb,
    const float* __restrict__ qw2, const float* __restrict__ qb2,
    const float* __restrict__ vw1, const float* __restrict__ vg,  const float* __restrict__ vb,
    const float* __restrict__ vw2, const float* __restrict__ vb2,
    const float* __restrict__ aw1, const float* __restrict__ ag,  const float* __restrict__ ab,
    const float* __restrict__ aw2, const float* __restrict__ ab2,
    const float* __restrict__ rw1, const float* __restrict__ rg1, const float* __restrict__ rb1,
    const float* __restrict__ rw2, const float* __restrict__ rg2, const float* __restrict__ rb2,
    const float* __restrict__ rw3, const float* __restrict__ rb3,
    const float* __restrict__ gw1, const float* __restrict__ gg,  const float* __restrict__ gb,
    const float* __restrict__ gw2, const float* __restrict__ gb2,
    float* __restrict__ out, int n)
{
    const int row = blockIdx.x * blockDim.x + threadIdx.x;
    if (row >= n) return;

    // ---- Phase A: stream rep once through BOTH 64-wide layer-1 matmuls ----
    // racc = rep @ rw1[0:128,:]   (residual branch layer 1, partial)
    // kacc = rep @ kw1            (key branch layer 1)
    float racc[64], kacc[64];
#pragma unroll
    for (int j = 0; j < 64; ++j) { racc[j] = 0.f; kacc[j] = 0.f; }

    const float4* rep4 = (const float4*)(rep + (size_t)row * 128);
    for (int k4 = 0; k4 < 32; ++k4) {   // rolled: keeps I$ footprint bounded
        const float4 x = rep4[k4];
        const float* rw = rw1 + (size_t)k4 * 4 * 64;
        const float* kw = kw1 + (size_t)k4 * 4 * 64;
#pragma unroll
        for (int j = 0; j < 64; ++j) {
            racc[j] = fmaf(x.x, rw[      j], racc[j]);
            racc[j] = fmaf(x.y, rw[ 64 + j], racc[j]);
            racc[j] = fmaf(x.z, rw[128 + j], racc[j]);
            racc[j] = fmaf(x.w, rw[192 + j], racc[j]);
            kacc[j] = fmaf(x.x, kw[      j], kacc[j]);
            kacc[j] = fmaf(x.y, kw[ 64 + j], kacc[j]);
            kacc[j] = fmaf(x.z, kw[128 + j], kacc[j]);
            kacc[j] = fmaf(x.w, kw[192 + j], kacc[j]);
        }
    }

    // pose (rows 128..133 of rw1) and opening (row 134) into residual layer 1
    float pv[6];
#pragma unroll
    for (int i = 0; i < 6; ++i) pv[i] = pose[(size_t)row * 6 + i];
    const float ov = opening[row];
#pragma unroll
    for (int kk2 = 0; kk2 < 6; ++kk2) {
#pragma unroll
        for (int j = 0; j < 64; ++j)
            racc[j] = fmaf(pv[kk2], rw1[(128 + kk2) * 64 + j], racc[j]);
    }
#pragma unroll
    for (int j = 0; j < 64; ++j)
        racc[j] = fmaf(ov, rw1[134 * 64 + j], racc[j]);

    // ---- key branch: LN -> ReLU -> Linear(+bias) ----
    ln_relu<64>(kacc, kg, kb);
    float key[32];
    matvec_bias<64, 32>(kacc, kw2, kb2, key);

    // ---- residual branch ----
    ln_relu<64>(racc, rg1, rb1);
    float h2[32];
    matvec<64, 32>(racc, rw2, h2);
    ln_relu<32>(h2, rg2, rb2);
    float residuals[16];
    matvec_bias<32, 16>(h2, rw3, rb3, residuals);

    // ---- query branch ----
    float q1[16];
    matvec<6, 16>(pv, qw1, q1);
    ln_relu<16>(q1, qg, qb);
    float query[32];
    matvec_bias<16, 32>(q1, qw2, qb2, query);

    // ---- value branch ----
    float v1[16];
#pragma unroll
    for (int j = 0; j < 16; ++j) v1[j] = ov * vw1[j];
    ln_relu<16>(v1, vg, vb);
    float value[32];
    matvec_bias<16, 32>(v1, vw2, vb2, value);

    // ---- attention combine: softmax(query*key) * value ----
    float s[32];
#pragma unroll
    for (int j = 0; j < 32; ++j) s[j] = query[j] * key[j];
    float mx = s[0];
#pragma unroll
    for (int j = 1; j < 32; ++j) mx = fmaxf(mx, s[j]);
    float sum = 0.f;
#pragma unroll
    for (int j = 0; j < 32; ++j) { s[j] = __expf(s[j] - mx); sum += s[j]; }
    const float inv = 1.0f / sum;
#pragma unroll
    for (int j = 0; j < 32; ++j) s[j] = s[j] * inv * value[j];

    // ---- attention head block ----
    float a1[32];
    matvec<32, 32>(s, aw1, a1);
    ln_relu<32>(a1, ag, ab);
    float att[16];
    matvec_bias<32, 16>(a1, aw2, ab2, att);

    // ---- get_value block on features = concat([att, residuals]) ----
    float g1[16];
#pragma unroll
    for (int j = 0; j < 16; ++j) g1[j] = 0.f;
#pragma unroll
    for (int k = 0; k < 16; ++k) {
        const float xv = att[k];
#pragma unroll
        for (int j = 0; j < 16; ++j) g1[j] = fmaf(xv, gw1[k * 16 + j], g1[j]);
    }
#pragma unroll
    for (int k = 0; k < 16; ++k) {
        const float xv = residuals[k];
#pragma unroll
        for (int j = 0; j < 16; ++j) g1[j] = fmaf(xv, gw1[(16 + k) * 16 + j], g1[j]);
    }
    ln_relu<16>(g1, gg, gb);
    float score = gb2[0];
#pragma unroll
    for (int k = 0; k < 16; ++k) score = fmaf(g1[k], gw2[k], score);

    out[row] = score;
}

extern "C" void kernel_launch(void* const* d_in, const int* in_sizes, int n_in,
                              void* d_out, int out_size, void* d_ws, size_t ws_size,
                              hipStream_t stream) {
    const float* rep     = (const float*)d_in[0];
    const float* pose    = (const float*)d_in[1];
    const float* opening = (const float*)d_in[2];
    const float* kw1 = (const float*)d_in[3];
    const float* kg  = (const float*)d_in[4];
    const float* kb  = (const float*)d_in[5];
    const float* kw2 = (const float*)d_in[6];
    const float* kb2 = (const float*)d_in[7];
    const float* qw1 = (const float*)d_in[8];
    const float* qg  = (const float*)d_in[9];
    const float* qb  = (const float*)d_in[10];
    const float* qw2 = (const float*)d_in[11];
    const float* qb2 = (const float*)d_in[12];
    const float* vw1 = (const float*)d_in[13];
    const float* vg  = (const float*)d_in[14];
    const float* vb  = (const float*)d_in[15];
    const float* vw2 = (const float*)d_in[16];
    const float* vb2 = (const float*)d_in[17];
    const float* aw1 = (const float*)d_in[18];
    const float* ag  = (const float*)d_in[19];
    const float* ab  = (const float*)d_in[20];
    const float* aw2 = (const float*)d_in[21];
    const float* ab2 = (const float*)d_in[22];
    const float* rw1 = (const float*)d_in[23];
    const float* rg1 = (const float*)d_in[24];
    const float* rb1 = (const float*)d_in[25];
    const float* rw2 = (const float*)d_in[26];
    const float* rg2 = (const float*)d_in[27];
    const float* rb2 = (const float*)d_in[28];
    const float* rw3 = (const float*)d_in[29];
    const float* rb3 = (const float*)d_in[30];
    const float* gw1 = (const float*)d_in[31];
    const float* gg  = (const float*)d_in[32];
    const float* gb  = (const float*)d_in[33];
    const float* gw2 = (const float*)d_in[34];
    const float* gb2 = (const float*)d_in[35];

    const int n = in_sizes[0] / 128;   // 524288 rows
    float* out = (float*)d_out;

    dim3 block(256);
    dim3 grid((n + 255) / 256);
    hipLaunchKernelGGL(opening_critic_kernel, grid, block, 0, stream,
                       rep, pose, opening,
                       kw1, kg, kb, kw2, kb2,
                       qw1, qg, qb, qw2, qb2,
                       vw1, vg, vb, vw2, vb2,
                       aw1, ag, ab, aw2, ab2,
                       rw1, rg1, rb1, rw2, rg2, rb2, rw3, rb3,
                       gw1, gg, gb, gw2, gb2,
                       out, n);
}

// Round 2
// 853.105 us; speedup vs baseline: 1.5082x; 1.5082x over previous
//
#include <hip/hip_runtime.h>
#include <hip/hip_bf16.h>
#include <math.h>

#define LN_EPS 1e-5f

typedef float v2f __attribute__((ext_vector_type(2)));

// LayerNorm over 2*D2 values held as v2f[D2], then *g+b, then ReLU (in place).
template<int D2>
__device__ __forceinline__ void ln_relu2(v2f (&v)[D2],
                                         const float* __restrict__ g,
                                         const float* __restrict__ b) {
    const float invD = 1.0f / (float)(2 * D2);
    float m = 0.f;
#pragma unroll
    for (int i = 0; i < D2; ++i) m += v[i].x + v[i].y;
    m *= invD;
    float var = 0.f;
#pragma unroll
    for (int i = 0; i < D2; ++i) {
        float dx = v[i].x - m, dy = v[i].y - m;
        var = fmaf(dx, dx, var);
        var = fmaf(dy, dy, var);
    }
    var *= invD;
    const float rs = rsqrtf(var + LN_EPS);
    const v2f* g2 = (const v2f*)g;
    const v2f* b2 = (const v2f*)b;
#pragma unroll
    for (int i = 0; i < D2; ++i) {
        v2f t = (v[i] - m) * rs * g2[i] + b2[i];
        v[i].x = fmaxf(t.x, 0.f);
        v[i].y = fmaxf(t.y, 0.f);
    }
}

// y[2*OUT2] = x[2*IN2] @ W[2*IN2, 2*OUT2], no bias. W row-major.
template<int IN2, int OUT2>
__device__ __forceinline__ void mv2(const v2f (&x)[IN2],
                                    const float* __restrict__ W,
                                    v2f (&y)[OUT2]) {
    const v2f* W2 = (const v2f*)W;
#pragma unroll
    for (int j = 0; j < OUT2; ++j) { v2f z; z.x = 0.f; z.y = 0.f; y[j] = z; }
#pragma unroll
    for (int k2 = 0; k2 < IN2; ++k2) {
        const float x0 = x[k2].x, x1 = x[k2].y;
#pragma unroll
        for (int j = 0; j < OUT2; ++j) {
            y[j] += x0 * W2[(2 * k2) * OUT2 + j];
            y[j] += x1 * W2[(2 * k2 + 1) * OUT2 + j];
        }
    }
}

// y[2*OUT2] = x[2*IN2] @ W + bias
template<int IN2, int OUT2>
__device__ __forceinline__ void mv2_bias(const v2f (&x)[IN2],
                                         const float* __restrict__ W,
                                         const float* __restrict__ bias,
                                         v2f (&y)[OUT2]) {
    const v2f* W2 = (const v2f*)W;
    const v2f* b2 = (const v2f*)bias;
#pragma unroll
    for (int j = 0; j < OUT2; ++j) y[j] = b2[j];
#pragma unroll
    for (int k2 = 0; k2 < IN2; ++k2) {
        const float x0 = x[k2].x, x1 = x[k2].y;
#pragma unroll
        for (int j = 0; j < OUT2; ++j) {
            y[j] += x0 * W2[(2 * k2) * OUT2 + j];
            y[j] += x1 * W2[(2 * k2 + 1) * OUT2 + j];
        }
    }
}

__global__ __launch_bounds__(256) void opening_critic_kernel(
    const float* __restrict__ rep,      // [N,128]
    const float* __restrict__ pose,     // [N,6]
    const float* __restrict__ opening,  // [N,1]
    const float* __restrict__ kw1, const float* __restrict__ kg,  const float* __restrict__ kb,
    const float* __restrict__ kw2, const float* __restrict__ kb2,
    const float* __restrict__ qw1, const float* __restrict__ qg,  const float* __restrict__ qb,
    const float* __restrict__ qw2, const float* __restrict__ qb2,
    const float* __restrict__ vw1, const float* __restrict__ vg,  const float* __restrict__ vb,
    const float* __restrict__ vw2, const float* __restrict__ vb2,
    const float* __restrict__ aw1, const float* __restrict__ ag,  const float* __restrict__ ab,
    const float* __restrict__ aw2, const float* __restrict__ ab2,
    const float* __restrict__ rw1, const float* __restrict__ rg1, const float* __restrict__ rb1,
    const float* __restrict__ rw2, const float* __restrict__ rg2, const float* __restrict__ rb2,
    const float* __restrict__ rw3, const float* __restrict__ rb3,
    const float* __restrict__ gw1, const float* __restrict__ gg,  const float* __restrict__ gb,
    const float* __restrict__ gw2, const float* __restrict__ gb2,
    float* __restrict__ out, int n)
{
    __shared__ v2f keybuf[16][256];   // 32 KB: parks key[32] between passes

    const int tid = threadIdx.x;
    const int gid = blockIdx.x * blockDim.x + tid;
    const bool active = (gid < n);
    const int row = active ? gid : (n - 1);

    const float4* rep4 = (const float4*)(rep + (size_t)row * 128);

    // ---------------- Pass A: kacc = rep @ kw1 (128->64) ----------------
    {
        v2f ka[32];
#pragma unroll
        for (int j = 0; j < 32; ++j) { v2f z; z.x = 0.f; z.y = 0.f; ka[j] = z; }

#pragma unroll 2
        for (int k4 = 0; k4 < 32; ++k4) {
            const float4 x = rep4[k4];
            const v2f* w = (const v2f*)(kw1 + (size_t)k4 * 4 * 64);
#pragma unroll
            for (int j = 0; j < 32; ++j) {
                ka[j] += x.x * w[      j];
                ka[j] += x.y * w[ 32 + j];
                ka[j] += x.z * w[ 64 + j];
                ka[j] += x.w * w[ 96 + j];
            }
        }

        ln_relu2<32>(ka, kg, kb);
        v2f key[16];
        mv2_bias<32, 16>(ka, kw2, kb2, key);
#pragma unroll
        for (int j = 0; j < 16; ++j) keybuf[j][tid] = key[j];
    }
    __syncthreads();   // force real LDS round-trip (frees key's registers)

    // small per-row inputs
    float pv[6];
#pragma unroll
    for (int i = 0; i < 6; ++i) pv[i] = pose[(size_t)row * 6 + i];
    const float ov = opening[row];

    // ---------------- Pass B: racc = [rep,pose,open] @ rw1 (135->64) ----------------
    v2f residuals[8];
    {
        v2f ra[32];
#pragma unroll
        for (int j = 0; j < 32; ++j) { v2f z; z.x = 0.f; z.y = 0.f; ra[j] = z; }

#pragma unroll 2
        for (int k4 = 0; k4 < 32; ++k4) {
            const float4 x = rep4[k4];
            const v2f* w = (const v2f*)(rw1 + (size_t)k4 * 4 * 64);
#pragma unroll
            for (int j = 0; j < 32; ++j) {
                ra[j] += x.x * w[      j];
                ra[j] += x.y * w[ 32 + j];
                ra[j] += x.z * w[ 64 + j];
                ra[j] += x.w * w[ 96 + j];
            }
        }
#pragma unroll
        for (int kk = 0; kk < 6; ++kk) {
            const v2f* w = (const v2f*)(rw1 + (128 + kk) * 64);
            const float xv = pv[kk];
#pragma unroll
            for (int j = 0; j < 32; ++j) ra[j] += xv * w[j];
        }
        {
            const v2f* w = (const v2f*)(rw1 + 134 * 64);
#pragma unroll
            for (int j = 0; j < 32; ++j) ra[j] += ov * w[j];
        }

        ln_relu2<32>(ra, rg1, rb1);
        v2f h2[16];
        mv2<32, 16>(ra, rw2, h2);
        ln_relu2<16>(h2, rg2, rb2);
        mv2_bias<16, 8>(h2, rw3, rb3, residuals);
    }

    // ---------------- query branch: 6 -> 16 -> 32 ----------------
    v2f query[16];
    {
        v2f q1[8];
        const v2f* qw1_2 = (const v2f*)qw1;
#pragma unroll
        for (int j = 0; j < 8; ++j) { v2f z; z.x = 0.f; z.y = 0.f; q1[j] = z; }
#pragma unroll
        for (int k = 0; k < 6; ++k) {
            const float xv = pv[k];
#pragma unroll
            for (int j = 0; j < 8; ++j) q1[j] += xv * qw1_2[k * 8 + j];
        }
        ln_relu2<8>(q1, qg, qb);
        mv2_bias<8, 16>(q1, qw2, qb2, query);
    }

    // ---------------- value branch: 1 -> 16 -> 32 ----------------
    v2f value[16];
    {
        v2f v1[8];
        const v2f* vw1_2 = (const v2f*)vw1;
#pragma unroll
        for (int j = 0; j < 8; ++j) v1[j] = ov * vw1_2[j];
        ln_relu2<8>(v1, vg, vb);
        mv2_bias<8, 16>(v1, vw2, vb2, value);
    }

    // ---------------- attention combine: softmax(q*k) * v ----------------
    v2f s[16];
#pragma unroll
    for (int j = 0; j < 16; ++j) s[j] = query[j] * keybuf[j][tid];
    float mx = -1e30f;
#pragma unroll
    for (int j = 0; j < 16; ++j) mx = fmaxf(mx, fmaxf(s[j].x, s[j].y));
    float sum = 0.f;
#pragma unroll
    for (int j = 0; j < 16; ++j) {
        s[j].x = __expf(s[j].x - mx);
        s[j].y = __expf(s[j].y - mx);
        sum += s[j].x + s[j].y;
    }
    const float inv = 1.0f / sum;
#pragma unroll
    for (int j = 0; j < 16; ++j) s[j] = s[j] * inv * value[j];

    // ---------------- attention head: 32 -> 32 -> 16 ----------------
    v2f att[8];
    {
        v2f a1[16];
        mv2<16, 16>(s, aw1, a1);
        ln_relu2<16>(a1, ag, ab);
        mv2_bias<16, 8>(a1, aw2, ab2, att);
    }

    // ---------------- get_value on concat([att, residuals]) : 32 -> 16 -> 1 ----------------
    float score;
    {
        v2f g1[8];
        const v2f* b2 = (const v2f*)gb;   // placeholder to keep types obvious
        (void)b2;
        const v2f* gw1_2 = (const v2f*)gw1;
        const v2f* gbias2 = (const v2f*)0;
        (void)gbias2;
#pragma unroll
        for (int j = 0; j < 8; ++j) { v2f z; z.x = 0.f; z.y = 0.f; g1[j] = z; }
#pragma unroll
        for (int k2 = 0; k2 < 8; ++k2) {
            const float x0 = att[k2].x, x1 = att[k2].y;
#pragma unroll
            for (int j = 0; j < 8; ++j) {
                g1[j] += x0 * gw1_2[(2 * k2) * 8 + j];
                g1[j] += x1 * gw1_2[(2 * k2 + 1) * 8 + j];
            }
        }
#pragma unroll
        for (int k2 = 0; k2 < 8; ++k2) {
            const float x0 = residuals[k2].x, x1 = residuals[k2].y;
#pragma unroll
            for (int j = 0; j < 8; ++j) {
                g1[j] += x0 * gw1_2[(16 + 2 * k2) * 8 + j];
                g1[j] += x1 * gw1_2[(16 + 2 * k2 + 1) * 8 + j];
            }
        }
        ln_relu2<8>(g1, gg, gb);
        score = gb2[0];
        const v2f* gw2_2 = (const v2f*)gw2;
#pragma unroll
        for (int k = 0; k < 8; ++k) {
            score = fmaf(g1[k].x, gw2_2[k].x, score);
            score = fmaf(g1[k].y, gw2_2[k].y, score);
        }
    }

    if (active) out[gid] = score;
}

extern "C" void kernel_launch(void* const* d_in, const int* in_sizes, int n_in,
                              void* d_out, int out_size, void* d_ws, size_t ws_size,
                              hipStream_t stream) {
    const float* rep     = (const float*)d_in[0];
    const float* pose    = (const float*)d_in[1];
    const float* opening = (const float*)d_in[2];
    const float* kw1 = (const float*)d_in[3];
    const float* kg  = (const float*)d_in[4];
    const float* kb  = (const float*)d_in[5];
    const float* kw2 = (const float*)d_in[6];
    const float* kb2 = (const float*)d_in[7];
    const float* qw1 = (const float*)d_in[8];
    const float* qg  = (const float*)d_in[9];
    const float* qb  = (const float*)d_in[10];
    const float* qw2 = (const float*)d_in[11];
    const float* qb2 = (const float*)d_in[12];
    const float* vw1 = (const float*)d_in[13];
    const float* vg  = (const float*)d_in[14];
    const float* vb  = (const float*)d_in[15];
    const float* vw2 = (const float*)d_in[16];
    const float* vb2 = (const float*)d_in[17];
    const float* aw1 = (const float*)d_in[18];
    const float* ag  = (const float*)d_in[19];
    const float* ab  = (const float*)d_in[20];
    const float* aw2 = (const float*)d_in[21];
    const float* ab2 = (const float*)d_in[22];
    const float* rw1 = (const float*)d_in[23];
    const float* rg1 = (const float*)d_in[24];
    const float* rb1 = (const float*)d_in[25];
    const float* rw2 = (const float*)d_in[26];
    const float* rg2 = (const float*)d_in[27];
    const float* rb2 = (const float*)d_in[28];
    const float* rw3 = (const float*)d_in[29];
    const float* rb3 = (const float*)d_in[30];
    const float* gw1 = (const float*)d_in[31];
    const float* gg  = (const float*)d_in[32];
    const float* gb  = (const float*)d_in[33];
    const float* gw2 = (const float*)d_in[34];
    const float* gb2 = (const float*)d_in[35];

    const int n = in_sizes[0] / 128;   // 524288 rows
    float* out = (float*)d_out;

    dim3 block(256);
    dim3 grid((n + 255) / 256);
    hipLaunchKernelGGL(opening_critic_kernel, grid, block, 0, stream,
                       rep, pose, opening,
                       kw1, kg, kb, kw2, kb2,
                       qw1, qg, qb, qw2, qb2,
                       vw1, vg, vb, vw2, vb2,
                       aw1, ag, ab, aw2, ab2,
                       rw1, rg1, rb1, rw2, rg2, rb2, rw3, rb3,
                       gw1, gg, gb, gw2, gb2,
                       out, n);
}